// Round 11
// baseline (75.086 us; speedup 1.0000x reference)
//
#include <hip/hip_runtime.h>
#include <hip/hip_fp16.h>

// ApproxConv2d via 256x256 LUT (approximate multiplier).
// out[b,o,y,x] = sum_{c,ky,kx} lut[ qx(b,c,y+ky-1,x+kx-1)*256 + qw(o,c,ky,kx) ] + bias[o]
// qx/qw = clip(rint(v*64), -128, 127) + 128; padding -> qx=128 -> lut row 128 = 0.
//
// v11 = v7's proven gather core (b32 o-pair rows, 12B stride -> all-32-bank
// spread, fastest measured: main ~43.5us) at 4 blocks/CU (16 waves/CU).
// v8/v10 showed b64 o-quad is SLOWER (even-bank starts, wider conflict
// exposure) and that occupancy was grid-limited (512 blocks = 2/CU). Here:
// quarter-image blocks (8 rows), grid 1024, LDS 40.1KB -> exactly 4/CU.
// T[pair][c][ky][qx] row = 12B = 3 words {h(o0 tap_k)|h(o1 tap_k)}; per
// (px,tap) one b32 feeds 2 MACs via __hadd2; fp16 partials -> f32 every 2
// channels. 4 channel-parities x 64 threads; per iter stage 4 channels' T
// (36864B, global_load_lds w=16), 2 barriers/iter (proven v7 schedule).

#define NT 256

__device__ __forceinline__ int quantize(float v) {
    // clip(rint(v*64), -128, 127) + 128; rintf = round-half-to-even = jnp.round
    int q = (int)rintf(v * 64.0f);
    q = q < -128 ? -128 : q;
    q = q > 127 ? 127 : q;
    return q + 128;
}

__device__ __forceinline__ void gll16(const void* g, void* l) {
    __builtin_amdgcn_global_load_lds(
        (const __attribute__((address_space(1))) unsigned int*)g,
        (__attribute__((address_space(3))) unsigned int*)l, 16, 0, 0);
}

// -------- build: T[pair][c][ky][qx] 12B tap-interleaved rows (v7-proven) ----
// 1024 blocks = (pair, 8-qx-row slice).
__global__ __launch_bounds__(NT, 2)
void build_T3(const float* __restrict__ w, const float* __restrict__ lut,
              unsigned int* __restrict__ T)
{
    __shared__ float band[8 * 257];
    __shared__ unsigned char qw2[2][576];

    const int tid = threadIdx.x;
    const int pair = blockIdx.x >> 5;       // 0..31
    const int qq = (blockIdx.x & 31) << 3;  // qx slice base (8 rows)

    for (int i = tid; i < 1152; i += NT) {
        int os = i >= 576;
        int idx = i - os * 576;
        qw2[os][idx] = (unsigned char)quantize(w[(pair * 2 + os) * 576 + idx]);
    }
    for (int i = tid; i < 8 * 256; i += NT) {
        int r = i >> 8, c2 = i & 255;
        band[r * 257 + c2] = lut[(qq + r) * 256 + c2];
    }
    __syncthreads();

    // 64c x 3ky x 8qx = 1536 items
    for (int it = 0; it < 6; ++it) {
        int idx = it * NT + tid;
        int c = idx / 24;
        int rem = idx - c * 24;
        int ky = rem >> 3;
        int qxl = rem & 7;
        const float* brow = band + qxl * 257;
        const unsigned char* q0 = &qw2[0][c * 9 + ky * 3];
        const unsigned char* q1 = &qw2[1][c * 9 + ky * 3];
        unsigned int* dst =
            T + ((size_t)((pair * 64 + c) * 3 + ky) * 256 + qq + qxl) * 3;
        #pragma unroll
        for (int k = 0; k < 3; ++k) {
            unsigned int h0 = __half_as_ushort(__float2half(brow[q0[k]]));
            unsigned int h1 = __half_as_ushort(__float2half(brow[q1[k]]));
            dst[k] = h0 | (h1 << 16);
        }
    }
}

// -------- main: block = (pair, b, quarter); 4 parities x 64 thr, 4-px -------
__global__ __launch_bounds__(NT, 4)
void approx_main(const float* __restrict__ x, const unsigned int* __restrict__ T,
                 const float* __restrict__ bias, float* __restrict__ out)
{
    __shared__ __align__(16) unsigned char Ts[36864];   // 4 channels' T
    __shared__ unsigned int plane[4][2][100];           // [parity][buf] 10r x 40B

    const int tid = threadIdx.x;
    const int bid = blockIdx.x;
    const int pair = bid & 31;               // XCD = bid%8 = pair%8
    const int g = bid >> 5;                  // 0..31
    const int b = g >> 2;
    const int qt = g & 3;                    // image quarter (8 output rows)

    const int parity = tid >> 6;             // channel parity (c mod 4)
    const int lt = tid & 63;
    const int yl = lt >> 3;                  // local row 0..7
    const int x0 = (lt & 7) << 2;            // 4-px strip base col
    const int yg = qt * 8 + yl;

    const char* Tg = (const char*)T + (size_t)pair * 589824;  // 64*3*256*12
    const float* xb = x + (size_t)b * 65536;

    for (int i = tid; i < 800; i += NT) ((unsigned int*)plane)[i] = 0x80808080u;

    // halo duty: every thread owns one (halo-row, col) byte of its parity
    const int hr = lt >> 5;                  // 0 top, 1 bottom
    const int hcol = lt & 31;
    const int hgrow = qt * 8 + (hr ? 8 : -1);
    const int hvalid = (hgrow >= 0 && hgrow < 32);
    const int hpr = hr ? 9 : 0;

    // prologue: pixels + halo for c = parity
    float4 xv = *(const float4*)(xb + parity * 1024 + yg * 32 + x0);
    float xh = hvalid ? xb[parity * 1024 + hgrow * 32 + hcol] : 0.f;

    __syncthreads();   // plane init complete

    const __half2 z2 = __float2half2_rn(0.f);
    __half2 acc2[4] = {z2, z2, z2, z2};      // per px: h(o0)|h(o1)
    float a0[4] = {0.f, 0.f, 0.f, 0.f};      // f32 partials o0
    float a1[4] = {0.f, 0.f, 0.f, 0.f};      // f32 partials o1

    for (int t = 0; t < 16; ++t) {
        const int buf = t & 1;
        // plane write for c = 4t+parity
        unsigned char* pb = (unsigned char*)plane[parity][buf];
        unsigned int pk = (unsigned int)quantize(xv.x) |
                          ((unsigned int)quantize(xv.y) << 8) |
                          ((unsigned int)quantize(xv.z) << 16) |
                          ((unsigned int)quantize(xv.w) << 24);
        *(unsigned int*)(pb + (yl + 1) * 40 + 4 + x0) = pk;
        if (hvalid) pb[hpr * 40 + 4 + hcol] = (unsigned char)quantize(xh);

        // stage 4 channels' T (36864B) for this t
        {
            const char* src = Tg + (size_t)t * 36864 + tid * 16;
            char* dst = (char*)Ts + tid * 16;
            #pragma unroll
            for (int k = 0; k < 9; ++k) gll16(src + k * 4096, dst + k * 4096);
        }
        // prefetch next iteration's pixels
        if (t < 15) {
            const int cn = 4 * (t + 1) + parity;
            xv = *(const float4*)(xb + cn * 1024 + yg * 32 + x0);
            if (hvalid) xh = xb[cn * 1024 + hgrow * 32 + hcol];
        }
        __syncthreads();   // gll drained; planes visible

        // compute channel c = 4t+parity
        const unsigned int* pl = plane[parity][buf];
        const char* Tc = (const char*)Ts + parity * 9216;
        #pragma unroll
        for (int ky = 0; ky < 3; ++ky) {
            const int w0 = (yl + ky) * 10 + (x0 >> 2);
            uint2 ua = *(const uint2*)&pl[w0];
            unsigned int uc = pl[w0 + 2];
            // m_j = qx of input col x0-1+j (col c at byte 4+c)
            int m0 = (int)(ua.x >> 24);
            int m1 = (int)(ua.y & 255u), m2 = (int)((ua.y >> 8) & 255u);
            int m3 = (int)((ua.y >> 16) & 255u), m4 = (int)(ua.y >> 24);
            int m5 = (int)(uc & 255u);
            const unsigned int* Tk = (const unsigned int*)(Tc + ky * 3072);
            // row m_j word k feeds px j-k (0<=j-k<=3)
            const unsigned int* R0 = Tk + m0 * 3;
            acc2[0] = __hadd2(acc2[0], *(const __half2*)&R0[0]);
            const unsigned int* R1 = Tk + m1 * 3;
            acc2[1] = __hadd2(acc2[1], *(const __half2*)&R1[0]);
            acc2[0] = __hadd2(acc2[0], *(const __half2*)&R1[1]);
            const unsigned int* R2 = Tk + m2 * 3;
            acc2[2] = __hadd2(acc2[2], *(const __half2*)&R2[0]);
            acc2[1] = __hadd2(acc2[1], *(const __half2*)&R2[1]);
            acc2[0] = __hadd2(acc2[0], *(const __half2*)&R2[2]);
            const unsigned int* R3 = Tk + m3 * 3;
            acc2[3] = __hadd2(acc2[3], *(const __half2*)&R3[0]);
            acc2[2] = __hadd2(acc2[2], *(const __half2*)&R3[1]);
            acc2[1] = __hadd2(acc2[1], *(const __half2*)&R3[2]);
            const unsigned int* R4 = Tk + m4 * 3;
            acc2[3] = __hadd2(acc2[3], *(const __half2*)&R4[1]);
            acc2[2] = __hadd2(acc2[2], *(const __half2*)&R4[2]);
            const unsigned int* R5 = Tk + m5 * 3;
            acc2[3] = __hadd2(acc2[3], *(const __half2*)&R5[2]);
        }
        // migrate fp16 partials to f32 every 2 channels (18-term chunks)
        if (t & 1) {
            #pragma unroll
            for (int p2 = 0; p2 < 4; ++p2) {
                a0[p2] += __low2float(acc2[p2]);
                a1[p2] += __high2float(acc2[p2]);
                acc2[p2] = z2;
            }
        }
        __syncthreads();   // compute done before next stage overwrites Ts
    }

    // cross-parity reduce via Ts (6KB), then bias + store
    float* red = (float*)Ts;
    if (parity) {
        #pragma unroll
        for (int p2 = 0; p2 < 4; ++p2) {
            red[(parity - 1) * 512 + lt * 8 + p2]     = a0[p2];
            red[(parity - 1) * 512 + lt * 8 + 4 + p2] = a1[p2];
        }
    }
    __syncthreads();
    if (!parity) {
        const int o0 = pair * 2;
        float bo0 = bias[o0], bo1 = bias[o0 + 1];
        float4 r0, r1;
        float* q0 = &r0.x; float* q1 = &r1.x;
        #pragma unroll
        for (int p2 = 0; p2 < 4; ++p2) {
            q0[p2] = a0[p2] + red[lt * 8 + p2] + red[512 + lt * 8 + p2]
                   + red[1024 + lt * 8 + p2] + bo0;
            q1[p2] = a1[p2] + red[lt * 8 + 4 + p2] + red[512 + lt * 8 + 4 + p2]
                   + red[1024 + lt * 8 + 4 + p2] + bo1;
        }
        *(float4*)(out + ((size_t)b * 64 + o0) * 1024 + yg * 32 + x0) = r0;
        *(float4*)(out + ((size_t)b * 64 + o0 + 1) * 1024 + yg * 32 + x0) = r1;
    }
}

// -------- fallback (proven v1, 98us): used if ws too small ------------------
#define BW1 61
__global__ __launch_bounds__(NT, 2)
void approxconv2d_v1(const float* __restrict__ x,
                     const float* __restrict__ w,
                     const float* __restrict__ bias,
                     const float* __restrict__ lut,
                     float* __restrict__ out)
{
    __shared__ float band[256 * BW1];
    __shared__ unsigned int plane[340];
    __shared__ unsigned char qwrow[576];
    __shared__ int s_min;

    const int tid = threadIdx.x;
    const int bid = blockIdx.x;
    const int b = bid >> 6;
    const int o = bid & 63;

    if (tid == 0) s_min = 255;
    for (int i = tid; i < 340; i += NT) plane[i] = 0x80808080u;
    __syncthreads();

    int lmin = 255;
    for (int i = tid; i < 576; i += NT) {
        int q = quantize(w[o * 576 + i]);
        qwrow[i] = (unsigned char)q;
        lmin = lmin < q ? lmin : q;
    }
    atomicMin(&s_min, lmin);
    __syncthreads();

    int cmin = s_min;
    if (cmin > 256 - BW1) cmin = 256 - BW1;

    for (int i = tid; i < 256 * BW1; i += NT) {
        int qx = i / BW1;
        int cc = i - qx * BW1;
        band[i] = lut[(qx << 8) + cmin + cc];
    }

    const int y  = tid >> 3;
    const int xq = tid & 7;
    const int x0 = xq << 2;

    float acc0 = 0.f, acc1 = 0.f, acc2 = 0.f, acc3 = 0.f;
    const float* xb = x + (size_t)b * 64 * 1024;
    unsigned char* pb = (unsigned char*)plane;

    for (int c = 0; c < 64; ++c) {
        __syncthreads();
        float4 xv = *(const float4*)(xb + c * 1024 + y * 32 + x0);
        int qa = quantize(xv.x), qb = quantize(xv.y);
        int qc = quantize(xv.z), qd = quantize(xv.w);
        int wbase = (y + 1) * 40 + x0 + 1;
        pb[wbase + 0] = (unsigned char)qa;
        pb[wbase + 1] = (unsigned char)qb;
        pb[wbase + 2] = (unsigned char)qc;
        pb[wbase + 3] = (unsigned char)qd;
        __syncthreads();

        const unsigned char* qwp = qwrow + c * 9;
        #pragma unroll
        for (int ky = 0; ky < 3; ++ky) {
            int ro = (y + ky) * 10 + xq;
            unsigned int r0 = plane[ro];
            unsigned int r1 = plane[ro + 1];
            int ee[6];
            ee[0] = (int)(r0 & 255u);
            ee[1] = (int)((r0 >> 8) & 255u);
            ee[2] = (int)((r0 >> 16) & 255u);
            ee[3] = (int)(r0 >> 24);
            ee[4] = (int)(r1 & 255u);
            ee[5] = (int)((r1 >> 8) & 255u);
            int pp[6];
            #pragma unroll
            for (int tt = 0; tt < 6; ++tt) pp[tt] = ee[tt] * BW1;
            #pragma unroll
            for (int kx = 0; kx < 3; ++kx) {
                int cq = (int)qwp[ky * 3 + kx];
                int cc = cq - cmin;
                if ((unsigned)cc < (unsigned)BW1) {
                    acc0 += band[pp[kx + 0] + cc];
                    acc1 += band[pp[kx + 1] + cc];
                    acc2 += band[pp[kx + 2] + cc];
                    acc3 += band[pp[kx + 3] + cc];
                } else {
                    acc0 += lut[(ee[kx + 0] << 8) + cq];
                    acc1 += lut[(ee[kx + 1] << 8) + cq];
                    acc2 += lut[(ee[kx + 2] << 8) + cq];
                    acc3 += lut[(ee[kx + 3] << 8) + cq];
                }
            }
        }
    }

    float bo = bias[o];
    float4 r;
    r.x = acc0 + bo; r.y = acc1 + bo; r.z = acc2 + bo; r.w = acc3 + bo;
    *(float4*)(out + (size_t)bid * 1024 + y * 32 + x0) = r;
}

extern "C" void kernel_launch(void* const* d_in, const int* in_sizes, int n_in,
                              void* d_out, int out_size, void* d_ws, size_t ws_size,
                              hipStream_t stream) {
    const float* x    = (const float*)d_in[0];
    const float* wgt  = (const float*)d_in[1];
    const float* bias = (const float*)d_in[2];
    const float* lut  = (const float*)d_in[3];
    float* out = (float*)d_out;

    const size_t T_BYTES = (size_t)32 * 64 * 3 * 256 * 12;   // 18,874,368
    if (ws_size >= T_BYTES) {
        hipLaunchKernelGGL(build_T3, dim3(1024), dim3(NT), 0, stream,
                           wgt, lut, (unsigned int*)d_ws);
        hipLaunchKernelGGL(approx_main, dim3(1024), dim3(NT), 0, stream,
                           x, (const unsigned int*)d_ws, bias, out);
    } else {
        hipLaunchKernelGGL(approxconv2d_v1, dim3(512), dim3(NT), 0, stream,
                           x, wgt, bias, lut, out);
    }
}

// Round 12
// 53.075 us; speedup vs baseline: 1.4147x; 1.4147x over previous
//
#include <hip/hip_runtime.h>
#include <hip/hip_fp16.h>

// ApproxConv2d via 256x256 LUT (approximate multiplier).
// out[b,o,y,x] = sum_{c,ky,kx} lut[ qx(b,c,y+ky-1,x+kx-1)*256 + qw(o,c,ky,kx) ] + bias[o]
// qx/qw = clip(rint(v*64), -128, 127) + 128; padding -> qx=128 -> lut row 128 = 0.
//
// v12 = v7's approx_main (proven best, ~43.5us: b32 o-pair tap rows at 12B
// stride -> all-32-bank spread; 8-px strips; 4 channel-parities x 64 threads;
// 36864B staged per 2-barrier iteration; fp16 __hadd2 accumulate with f32
// migration every 2 channels) + v11's 1024-block build_T3 (same table,
// half the per-block work, ~4-5us vs 9).
// Ladder evidence: b64/b96 widening, occupancy changes (1,2,4 blk/CU),
// counted-vmcnt dbuf, resident-T, and atomic reduction all lost or tied ->
// v7's config is the LDS random-gather local optimum (2B/MAC, pipe ~100%).

#define NT 256

__device__ __forceinline__ int quantize(float v) {
    // clip(rint(v*64), -128, 127) + 128; rintf = round-half-to-even = jnp.round
    int q = (int)rintf(v * 64.0f);
    q = q < -128 ? -128 : q;
    q = q > 127 ? 127 : q;
    return q + 128;
}

__device__ __forceinline__ void gll16(const void* g, void* l) {
    __builtin_amdgcn_global_load_lds(
        (const __attribute__((address_space(1))) unsigned int*)g,
        (__attribute__((address_space(3))) unsigned int*)l, 16, 0, 0);
}

// -------- build: T[pair][c][ky][qx] 12B tap-interleaved rows ----------------
// 1024 blocks = (pair, 8-qx-row slice). Proven in v11 (same output as v7's).
__global__ __launch_bounds__(NT, 2)
void build_T3(const float* __restrict__ w, const float* __restrict__ lut,
              unsigned int* __restrict__ T)
{
    __shared__ float band[8 * 257];
    __shared__ unsigned char qw2[2][576];

    const int tid = threadIdx.x;
    const int pair = blockIdx.x >> 5;       // 0..31
    const int qq = (blockIdx.x & 31) << 3;  // qx slice base (8 rows)

    for (int i = tid; i < 1152; i += NT) {
        int os = i >= 576;
        int idx = i - os * 576;
        qw2[os][idx] = (unsigned char)quantize(w[(pair * 2 + os) * 576 + idx]);
    }
    for (int i = tid; i < 8 * 256; i += NT) {
        int r = i >> 8, c2 = i & 255;
        band[r * 257 + c2] = lut[(qq + r) * 256 + c2];
    }
    __syncthreads();

    // 64c x 3ky x 8qx = 1536 items
    for (int it = 0; it < 6; ++it) {
        int idx = it * NT + tid;
        int c = idx / 24;
        int rem = idx - c * 24;
        int ky = rem >> 3;
        int qxl = rem & 7;
        const float* brow = band + qxl * 257;
        const unsigned char* q0 = &qw2[0][c * 9 + ky * 3];
        const unsigned char* q1 = &qw2[1][c * 9 + ky * 3];
        unsigned int* dst =
            T + ((size_t)((pair * 64 + c) * 3 + ky) * 256 + qq + qxl) * 3;
        #pragma unroll
        for (int k = 0; k < 3; ++k) {
            unsigned int h0 = __half_as_ushort(__float2half(brow[q0[k]]));
            unsigned int h1 = __half_as_ushort(__float2half(brow[q1[k]]));
            dst[k] = h0 | (h1 << 16);
        }
    }
}

// -------- main: v7 verbatim. block = (b, pair, half); 4 parities x 64 thr ---
__global__ __launch_bounds__(NT, 2)
void approx_main(const float* __restrict__ x, const unsigned int* __restrict__ T,
                 const float* __restrict__ bias, float* __restrict__ out)
{
    __shared__ __align__(16) unsigned char Ts[36864];   // 4 channels x 9216B
    __shared__ unsigned int plane[4][2][180];           // [parity][buf] 18r x 40B

    const int tid = threadIdx.x;
    const int bid = blockIdx.x;
    const int pair = bid & 31;               // XCD = bid%8 = pair%8
    const int bh = bid >> 5;                 // 0..15
    const int b = bh >> 1;
    const int h = bh & 1;

    const int parity = tid >> 6;             // channel parity (c mod 4)
    const int lt = tid & 63;
    const int yl = lt >> 2;                  // local out row 0..15
    const int xs = lt & 3;
    const int x0 = xs << 3;                  // 8-px strip base col
    const int yg = (h << 4) + yl;

    const char* Tg = (const char*)T + (size_t)pair * 589824;  // 64*3*256*12
    const float* xb = x + (size_t)b * 65536;

    const int halo_g  = h ? 15 : 16;         // real input row staged as halo
    const int halo_pr = h ? 0  : 17;         // plane row it lands in

    for (int i = tid; i < 1440; i += NT) ((unsigned int*)plane)[i] = 0x80808080u;

    // prologue: prefetch c = parity pixels
    float4 xv0 = *(const float4*)(xb + parity * 1024 + yg * 32 + x0);
    float4 xv1 = *(const float4*)(xb + parity * 1024 + yg * 32 + x0 + 4);
    float xh = (lt < 32) ? xb[parity * 1024 + halo_g * 32 + lt] : 0.f;

    __syncthreads();   // plane init complete

    const __half2 z2 = __float2half2_rn(0.f);
    float a32[8], b32[8];
    __half2 acc2[8];
    #pragma unroll
    for (int k = 0; k < 8; ++k) { a32[k] = 0.f; b32[k] = 0.f; acc2[k] = z2; }

    for (int t = 0; t < 16; ++t) {
        const int buf = t & 1;
        // plane write (this parity's channel c = 4t+parity)
        unsigned char* pb = (unsigned char*)plane[parity][buf];
        unsigned int pk0 = (unsigned int)quantize(xv0.x) |
                           ((unsigned int)quantize(xv0.y) << 8) |
                           ((unsigned int)quantize(xv0.z) << 16) |
                           ((unsigned int)quantize(xv0.w) << 24);
        unsigned int pk1 = (unsigned int)quantize(xv1.x) |
                           ((unsigned int)quantize(xv1.y) << 8) |
                           ((unsigned int)quantize(xv1.z) << 16) |
                           ((unsigned int)quantize(xv1.w) << 24);
        *(unsigned int*)(pb + (yl + 1) * 40 + 4 + x0)     = pk0;
        *(unsigned int*)(pb + (yl + 1) * 40 + 4 + x0 + 4) = pk1;
        if (lt < 32) pb[halo_pr * 40 + 4 + lt] = (unsigned char)quantize(xh);

        // stage 4 channels' T (36864B) for this t
        {
            const char* src = Tg + t * 36864 + tid * 16;
            char* dst = (char*)Ts + tid * 16;
            #pragma unroll
            for (int k = 0; k < 9; ++k) gll16(src + k * 4096, dst + k * 4096);
        }
        // prefetch next channel's pixels
        if (t < 15) {
            const int c1 = 4 * (t + 1) + parity;
            xv0 = *(const float4*)(xb + c1 * 1024 + yg * 32 + x0);
            xv1 = *(const float4*)(xb + c1 * 1024 + yg * 32 + x0 + 4);
            if (lt < 32) xh = xb[c1 * 1024 + halo_g * 32 + lt];
        }
        __syncthreads();   // gll drained; planes visible

        // compute channel c = 4t+parity
        const unsigned int* pl = plane[parity][buf];
        const char* Tc = (const char*)Ts + parity * 9216;
        #pragma unroll
        for (int ky = 0; ky < 3; ++ky) {
            const int prow = (yl + ky) * 10 + (x0 >> 2);
            uint2 ua = *(const uint2*)&pl[prow];       // cols x0-4..x0-1 | x0..x0+3
            uint2 ub = *(const uint2*)&pl[prow + 2];   // cols x0+4..x0+7 | x0+8..
            int m[10];
            m[0] = (int)(ua.x >> 24);
            m[1] = (int)(ua.y & 255u);  m[2] = (int)((ua.y >> 8) & 255u);
            m[3] = (int)((ua.y >> 16) & 255u); m[4] = (int)(ua.y >> 24);
            m[5] = (int)(ub.x & 255u);  m[6] = (int)((ub.x >> 8) & 255u);
            m[7] = (int)((ub.x >> 16) & 255u); m[8] = (int)(ub.x >> 24);
            m[9] = (int)(ub.y & 255u);
            const char* Tk = Tc + ky * 3072;
            #pragma unroll
            for (int j = 0; j < 10; ++j) {
                const unsigned int* R = (const unsigned int*)(Tk + m[j] * 12);
                // w_k = half(o0 tap_k) | half(o1 tap_k)<<16; tap kx feeds px j-kx
                if (j <= 7) {
                    unsigned int w0 = R[0];
                    acc2[j] = __hadd2(acc2[j], *(const __half2*)&w0);
                }
                if (j >= 1 && j <= 8) {
                    unsigned int w1 = R[1];
                    acc2[j - 1] = __hadd2(acc2[j - 1], *(const __half2*)&w1);
                }
                if (j >= 2) {
                    unsigned int w2 = R[2];
                    acc2[j - 2] = __hadd2(acc2[j - 2], *(const __half2*)&w2);
                }
            }
        }
        // migrate fp16 partials to f32 every 2 channels (bounded rounding)
        if (t & 1) {
            #pragma unroll
            for (int k = 0; k < 8; ++k) {
                a32[k] += __low2float(acc2[k]);
                b32[k] += __high2float(acc2[k]);
                acc2[k] = z2;
            }
        }
        __syncthreads();   // compute done before next stage overwrites Ts
    }

    // cross-parity reduce: parities 1..3 dump, parity 0 sums + bias + store
    float* red = (float*)Ts;
    if (parity) {
        #pragma unroll
        for (int k = 0; k < 8; ++k) {
            red[(parity - 1) * 1024 + lt * 16 + k]     = a32[k];
            red[(parity - 1) * 1024 + lt * 16 + 8 + k] = b32[k];
        }
    }
    __syncthreads();
    if (!parity) {
        const int o0 = pair * 2;
        float bo0 = bias[o0], bo1 = bias[o0 + 1];
        float r0[8], r1[8];
        #pragma unroll
        for (int k = 0; k < 8; ++k) {
            r0[k] = a32[k] + red[lt * 16 + k] + red[1024 + lt * 16 + k]
                  + red[2048 + lt * 16 + k] + bo0;
            r1[k] = b32[k] + red[lt * 16 + 8 + k] + red[1024 + lt * 16 + 8 + k]
                  + red[2048 + lt * 16 + 8 + k] + bo1;
        }
        float* p0 = out + ((size_t)b * 64 + o0) * 1024 + yg * 32 + x0;
        *(float4*)(p0)     = make_float4(r0[0], r0[1], r0[2], r0[3]);
        *(float4*)(p0 + 4) = make_float4(r0[4], r0[5], r0[6], r0[7]);
        float* p1 = p0 + 1024;
        *(float4*)(p1)     = make_float4(r1[0], r1[1], r1[2], r1[3]);
        *(float4*)(p1 + 4) = make_float4(r1[4], r1[5], r1[6], r1[7]);
    }
}

// -------- fallback (proven v1, 98us): used if ws too small ------------------
#define BW1 61
__global__ __launch_bounds__(NT, 2)
void approxconv2d_v1(const float* __restrict__ x,
                     const float* __restrict__ w,
                     const float* __restrict__ bias,
                     const float* __restrict__ lut,
                     float* __restrict__ out)
{
    __shared__ float band[256 * BW1];
    __shared__ unsigned int plane[340];
    __shared__ unsigned char qwrow[576];
    __shared__ int s_min;

    const int tid = threadIdx.x;
    const int bid = blockIdx.x;
    const int b = bid >> 6;
    const int o = bid & 63;

    if (tid == 0) s_min = 255;
    for (int i = tid; i < 340; i += NT) plane[i] = 0x80808080u;
    __syncthreads();

    int lmin = 255;
    for (int i = tid; i < 576; i += NT) {
        int q = quantize(w[o * 576 + i]);
        qwrow[i] = (unsigned char)q;
        lmin = lmin < q ? lmin : q;
    }
    atomicMin(&s_min, lmin);
    __syncthreads();

    int cmin = s_min;
    if (cmin > 256 - BW1) cmin = 256 - BW1;

    for (int i = tid; i < 256 * BW1; i += NT) {
        int qx = i / BW1;
        int cc = i - qx * BW1;
        band[i] = lut[(qx << 8) + cmin + cc];
    }

    const int y  = tid >> 3;
    const int xq = tid & 7;
    const int x0 = xq << 2;

    float acc0 = 0.f, acc1 = 0.f, acc2 = 0.f, acc3 = 0.f;
    const float* xb = x + (size_t)b * 64 * 1024;
    unsigned char* pb = (unsigned char*)plane;

    for (int c = 0; c < 64; ++c) {
        __syncthreads();
        float4 xv = *(const float4*)(xb + c * 1024 + y * 32 + x0);
        int qa = quantize(xv.x), qb = quantize(xv.y);
        int qc = quantize(xv.z), qd = quantize(xv.w);
        int wbase = (y + 1) * 40 + x0 + 1;
        pb[wbase + 0] = (unsigned char)qa;
        pb[wbase + 1] = (unsigned char)qb;
        pb[wbase + 2] = (unsigned char)qc;
        pb[wbase + 3] = (unsigned char)qd;
        __syncthreads();

        const unsigned char* qwp = qwrow + c * 9;
        #pragma unroll
        for (int ky = 0; ky < 3; ++ky) {
            int ro = (y + ky) * 10 + xq;
            unsigned int r0 = plane[ro];
            unsigned int r1 = plane[ro + 1];
            int ee[6];
            ee[0] = (int)(r0 & 255u);
            ee[1] = (int)((r0 >> 8) & 255u);
            ee[2] = (int)((r0 >> 16) & 255u);
            ee[3] = (int)(r0 >> 24);
            ee[4] = (int)(r1 & 255u);
            ee[5] = (int)((r1 >> 8) & 255u);
            int pp[6];
            #pragma unroll
            for (int tt = 0; tt < 6; ++tt) pp[tt] = ee[tt] * BW1;
            #pragma unroll
            for (int kx = 0; kx < 3; ++kx) {
                int cq = (int)qwp[ky * 3 + kx];
                int cc = cq - cmin;
                if ((unsigned)cc < (unsigned)BW1) {
                    acc0 += band[pp[kx + 0] + cc];
                    acc1 += band[pp[kx + 1] + cc];
                    acc2 += band[pp[kx + 2] + cc];
                    acc3 += band[pp[kx + 3] + cc];
                } else {
                    acc0 += lut[(ee[kx + 0] << 8) + cq];
                    acc1 += lut[(ee[kx + 1] << 8) + cq];
                    acc2 += lut[(ee[kx + 2] << 8) + cq];
                    acc3 += lut[(ee[kx + 3] << 8) + cq];
                }
            }
        }
    }

    float bo = bias[o];
    float4 r;
    r.x = acc0 + bo; r.y = acc1 + bo; r.z = acc2 + bo; r.w = acc3 + bo;
    *(float4*)(out + (size_t)bid * 1024 + y * 32 + x0) = r;
}

extern "C" void kernel_launch(void* const* d_in, const int* in_sizes, int n_in,
                              void* d_out, int out_size, void* d_ws, size_t ws_size,
                              hipStream_t stream) {
    const float* x    = (const float*)d_in[0];
    const float* wgt  = (const float*)d_in[1];
    const float* bias = (const float*)d_in[2];
    const float* lut  = (const float*)d_in[3];
    float* out = (float*)d_out;

    const size_t T_BYTES = (size_t)32 * 64 * 3 * 256 * 12;   // 18,874,368
    if (ws_size >= T_BYTES) {
        hipLaunchKernelGGL(build_T3, dim3(1024), dim3(NT), 0, stream,
                           wgt, lut, (unsigned int*)d_ws);
        hipLaunchKernelGGL(approx_main, dim3(512), dim3(NT), 0, stream,
                           x, (const unsigned int*)d_ws, bias, out);
    } else {
        hipLaunchKernelGGL(approxconv2d_v1, dim3(512), dim3(NT), 0, stream,
                           x, wgt, bias, lut, out);
    }
}